// Round 2
// baseline (354.807 us; speedup 1.0000x reference)
//
#include <hip/hip_runtime.h>
#include <math.h>

typedef __bf16 bf16;
typedef bf16 bf16x8 __attribute__((ext_vector_type(8)));
typedef bf16 bf16x4 __attribute__((ext_vector_type(4)));
typedef float f32x4 __attribute__((ext_vector_type(4)));

// Problem constants
#define T_DIM 1024
#define B_DIM 4
#define E_DIM 512
#define H_DIM 8
#define HD_DIM 64
#define BH_DIM 32

__device__ __forceinline__ f32x4 mfma16(bf16x8 a, bf16x8 b, f32x4 c) {
    return __builtin_amdgcn_mfma_f32_16x16x32_bf16(a, b, c, 0, 0, 0);
}

__device__ __forceinline__ bf16x4 cvt4(f32x4 v) {
    bf16x4 o;
    o[0] = (bf16)v[0]; o[1] = (bf16)v[1]; o[2] = (bf16)v[2]; o[3] = (bf16)v[3];
    return o;
}

// ---------------------------------------------------------------------------
// C = A * Bt^T + bias.  A:[M,K] fp32 row-major, Bt:[N,K] fp32 row-major
// (weight as stored), bias:[N] fp32.  Compute in bf16 MFMA, fp32 accumulate.
// mode 0: write out[m*N+n] (fp32)
// mode 1: qkv scatter to bf16 [BH,T,HD] buffers; q scaled by 1/8.
// Tiles: 64x64 per block (256 threads = 4 waves 2x2), K-step 64.
// ---------------------------------------------------------------------------
__global__ __launch_bounds__(256)
void gemm_bt(const float* __restrict__ A, const float* __restrict__ Bt,
             const float* __restrict__ bias, int K, int N, int mode,
             float* __restrict__ out, bf16* __restrict__ qb,
             bf16* __restrict__ kb, bf16* __restrict__ vb) {
    __shared__ __align__(16) bf16 As[64 * 72];
    __shared__ __align__(16) bf16 Bs[64 * 72];
    const int tid  = threadIdx.x;
    const int lane = tid & 63;
    const int wave = tid >> 6;
    const int quad = lane >> 4;
    const int l15  = lane & 15;
    const int wm = wave & 1, wn = wave >> 1;
    const int m0 = blockIdx.x * 64, n0 = blockIdx.y * 64;

    f32x4 acc[2][2] = {};

    const int sr = tid >> 2;          // 0..63 (row)
    const int sc = (tid & 3) * 16;    // 0,16,32,48 (col block of 16 floats)

    for (int k0 = 0; k0 < K; k0 += 64) {
#pragma unroll
        for (int j = 0; j < 4; j++) {
            f32x4 av = *(const f32x4*)&A[(long)(m0 + sr) * K + k0 + sc + j * 4];
            *(bf16x4*)&As[sr * 72 + sc + j * 4] = cvt4(av);
            f32x4 bv = *(const f32x4*)&Bt[(long)(n0 + sr) * K + k0 + sc + j * 4];
            *(bf16x4*)&Bs[sr * 72 + sc + j * 4] = cvt4(bv);
        }
        __syncthreads();
#pragma unroll
        for (int kk = 0; kk < 64; kk += 32) {
            bf16x8 a0 = *(const bf16x8*)&As[(wm * 32 + l15) * 72 + kk + quad * 8];
            bf16x8 a1 = *(const bf16x8*)&As[(wm * 32 + 16 + l15) * 72 + kk + quad * 8];
            bf16x8 b0 = *(const bf16x8*)&Bs[(wn * 32 + l15) * 72 + kk + quad * 8];
            bf16x8 b1 = *(const bf16x8*)&Bs[(wn * 32 + 16 + l15) * 72 + kk + quad * 8];
            acc[0][0] = mfma16(a0, b0, acc[0][0]);
            acc[0][1] = mfma16(a0, b1, acc[0][1]);
            acc[1][0] = mfma16(a1, b0, acc[1][0]);
            acc[1][1] = mfma16(a1, b1, acc[1][1]);
        }
        __syncthreads();
    }

    // Epilogue.  C/D layout: col = lane&15 (n), row = quad*4 + r (m).
#pragma unroll
    for (int mb = 0; mb < 2; mb++) {
#pragma unroll
        for (int nb = 0; nb < 2; nb++) {
            int n = n0 + wn * 32 + nb * 16 + l15;
            float bv = bias[n];
#pragma unroll
            for (int r = 0; r < 4; r++) {
                int m = m0 + wm * 32 + mb * 16 + quad * 4 + r;
                float v = acc[mb][nb][r] + bv;
                if (mode == 0) {
                    out[(long)m * N + n] = v;
                } else {
                    int t = m >> 2, b = m & 3;
                    int sec = n >> 9, j = n & 511;
                    int h = j >> 6, hd = j & 63;
                    long idx = ((long)(b * 8 + h) * T_DIM + t) * HD_DIM + hd;
                    if (sec == 0)      qb[idx] = (bf16)(v * 0.125f);  // 1/sqrt(64)
                    else if (sec == 1) kb[idx] = (bf16)v;
                    else               vb[idx] = (bf16)v;
                }
            }
        }
    }
}

// ---------------------------------------------------------------------------
// Flash-style attention with additive bias from dist[B,T,T,H] (fp32).
// Block = (bh, qtile of 64 rows), 256 threads = 4 waves, wave owns 16 Q-rows.
// Writes ctx[T][B][E] (fp32) with e = h*64+hd.
// ---------------------------------------------------------------------------
__global__ __launch_bounds__(256)
void attn_kernel(const bf16* __restrict__ qb, const bf16* __restrict__ kb,
                 const bf16* __restrict__ vb, const float* __restrict__ dist,
                 float* __restrict__ ctx) {
    __shared__ __align__(16) bf16 Ks[64 * 72];
    __shared__ __align__(16) bf16 Vts[64 * 72];
    __shared__ __align__(16) bf16 Ps[4 * 16 * 72];
    const int tid  = threadIdx.x;
    const int lane = tid & 63;
    const int wave = tid >> 6;
    const int quad = lane >> 4;
    const int l15  = lane & 15;
    const int bh = blockIdx.x;      // 0..31
    const int qt = blockIdx.y;      // 0..15
    const int b = bh >> 3, h = bh & 7;
    const int qrow = qt * 64 + wave * 16 + l15;   // A-operand row (m = lane&15)

    // Q fragments: A[m=lane&15][k=quad*8+j]
    bf16x8 qa0 = *(const bf16x8*)&qb[((long)bh * T_DIM + qrow) * HD_DIM + quad * 8];
    bf16x8 qa1 = *(const bf16x8*)&qb[((long)bh * T_DIM + qrow) * HD_DIM + 32 + quad * 8];

    f32x4 oacc[4] = {};            // 4 hd-blocks of 16
    float mrun[4], lrun[4];        // per C-row (quad*4 + r)
#pragma unroll
    for (int r = 0; r < 4; r++) { mrun[r] = -INFINITY; lrun[r] = 0.f; }

    const int r0 = tid >> 3;          // 0..31
    const int c0 = (tid & 7) * 8;     // 0..56

    for (int st = 0; st < T_DIM; st += 64) {
        // Stage K tile [s_local][hd]
        *(bf16x8*)&Ks[r0 * 72 + c0] =
            *(const bf16x8*)&kb[((long)bh * T_DIM + st + r0) * HD_DIM + c0];
        *(bf16x8*)&Ks[(r0 + 32) * 72 + c0] =
            *(const bf16x8*)&kb[((long)bh * T_DIM + st + r0 + 32) * HD_DIM + c0];
        // Stage V tile transposed: Vts[hd][s_local]
        {
            bf16x8 v0 = *(const bf16x8*)&vb[((long)bh * T_DIM + st + r0) * HD_DIM + c0];
            bf16x8 v1 = *(const bf16x8*)&vb[((long)bh * T_DIM + st + r0 + 32) * HD_DIM + c0];
#pragma unroll
            for (int j = 0; j < 8; j++) {
                Vts[(c0 + j) * 72 + r0]      = v0[j];
                Vts[(c0 + j) * 72 + r0 + 32] = v1[j];
            }
        }
        __syncthreads();

        // S = Q*K^T  (M=16 q-rows, N=64 s, K=64 hd)
        f32x4 sacc[4] = {};
#pragma unroll
        for (int kk = 0; kk < 64; kk += 32) {
            bf16x8 a = (kk == 0) ? qa0 : qa1;
#pragma unroll
            for (int nb = 0; nb < 4; nb++) {
                bf16x8 bfr = *(const bf16x8*)&Ks[(nb * 16 + l15) * 72 + kk + quad * 8];
                sacc[nb] = mfma16(a, bfr, sacc[nb]);
            }
        }

        // Add bias (dist strided by H in last dim, fp32)
        float sv[4][4];
#pragma unroll
        for (int nb = 0; nb < 4; nb++) {
            int s = st + nb * 16 + l15;
#pragma unroll
            for (int r = 0; r < 4; r++) {
                int tq = qt * 64 + wave * 16 + quad * 4 + r;
                float d = dist[(((long)b * T_DIM + tq) * T_DIM + s) * H_DIM + h];
                sv[nb][r] = sacc[nb][r] + d;
            }
        }

        // Online softmax per row (row spread over the quad's 16 lanes)
#pragma unroll
        for (int r = 0; r < 4; r++) {
            float rm = fmaxf(fmaxf(sv[0][r], sv[1][r]), fmaxf(sv[2][r], sv[3][r]));
#pragma unroll
            for (int msk = 1; msk < 16; msk <<= 1)
                rm = fmaxf(rm, __shfl_xor(rm, msk));
            float mnew  = fmaxf(mrun[r], rm);
            float alpha = __expf(mrun[r] - mnew);
            mrun[r] = mnew;
            float rs = 0.f;
#pragma unroll
            for (int nb = 0; nb < 4; nb++) {
                float p = __expf(sv[nb][r] - mnew);
                sv[nb][r] = p;
                rs += p;
            }
#pragma unroll
            for (int msk = 1; msk < 16; msk <<= 1)
                rs += __shfl_xor(rs, msk);
            lrun[r] = lrun[r] * alpha + rs;
#pragma unroll
            for (int nb = 0; nb < 4; nb++)
                oacc[nb][r] *= alpha;
        }

        // P: C-layout -> LDS -> A-operand layout
        bf16* pw = &Ps[wave * 16 * 72];
#pragma unroll
        for (int nb = 0; nb < 4; nb++)
#pragma unroll
            for (int r = 0; r < 4; r++)
                pw[(quad * 4 + r) * 72 + nb * 16 + l15] = (bf16)sv[nb][r];
        __syncthreads();   // order P writes before A-fragment reads

        // O += P * V   (M=16 q-rows, N=64 hd, K=64 s)
#pragma unroll
        for (int kk = 0; kk < 64; kk += 32) {
            bf16x8 ap = *(const bf16x8*)&pw[l15 * 72 + kk + quad * 8];
#pragma unroll
            for (int nb = 0; nb < 4; nb++) {
                bf16x8 bv2 = *(const bf16x8*)&Vts[(nb * 16 + l15) * 72 + kk + quad * 8];
                oacc[nb] = mfma16(ap, bv2, oacc[nb]);
            }
        }
        __syncthreads();
    }

    // Epilogue: normalize and write ctx[t][b][h*64+hd] (fp32)
#pragma unroll
    for (int nb = 0; nb < 4; nb++) {
#pragma unroll
        for (int r = 0; r < 4; r++) {
            int t  = qt * 64 + wave * 16 + quad * 4 + r;
            int hd = nb * 16 + l15;
            float o = oacc[nb][r] / lrun[r];
            ctx[((long)t * B_DIM + b) * E_DIM + h * HD_DIM + hd] = o;
        }
    }
}

// ---------------------------------------------------------------------------
extern "C" void kernel_launch(void* const* d_in, const int* in_sizes, int n_in,
                              void* d_out, int out_size, void* d_ws, size_t ws_size,
                              hipStream_t stream) {
    const float* query = (const float*)d_in[0];   // [T,B,E]
    const float* dist  = (const float*)d_in[1];   // [B,T,T,H]
    const float* win   = (const float*)d_in[2];   // [3E,E]
    const float* bin   = (const float*)d_in[3];   // [3E]
    const float* wout  = (const float*)d_in[4];   // [E,E]
    const float* bout  = (const float*)d_in[5];   // [E]
    float* out = (float*)d_out;                   // [T,B,E]

    bf16* qb  = (bf16*)d_ws;                      // 3x bf16 [BH,T,HD] = 12 MB
    bf16* kb  = qb + (1 << 21);
    bf16* vb  = kb + (1 << 21);
    float* ctx = (float*)(vb + (1 << 21));        // fp32 [T,B,E] = 8 MB

    // QKV in-projection: M=4096, N=1536, K=512
    gemm_bt<<<dim3(64, 24), 256, 0, stream>>>(query, win, bin, 512, 1536, 1,
                                              nullptr, qb, kb, vb);
    // Attention: 32 (b*H) x 16 q-tiles
    attn_kernel<<<dim3(32, 16), 256, 0, stream>>>(qb, kb, vb, dist, ctx);
    // Out-projection: M=4096, N=512, K=512
    gemm_bt<<<dim3(64, 8), 256, 0, stream>>>(ctx, wout, bout, 512, 512, 0,
                                             out, nullptr, nullptr, nullptr);
}

// Round 3
// 315.320 us; speedup vs baseline: 1.1252x; 1.1252x over previous
//
#include <hip/hip_runtime.h>
#include <math.h>

typedef __bf16 bf16;
typedef bf16 bf16x8 __attribute__((ext_vector_type(8)));
typedef bf16 bf16x4 __attribute__((ext_vector_type(4)));
typedef float f32x4 __attribute__((ext_vector_type(4)));

// Problem constants
#define T_DIM 1024
#define B_DIM 4
#define E_DIM 512
#define H_DIM 8
#define HD_DIM 64
#define BH_DIM 32

__device__ __forceinline__ f32x4 mfma16(bf16x8 a, bf16x8 b, f32x4 c) {
    return __builtin_amdgcn_mfma_f32_16x16x32_bf16(a, b, c, 0, 0, 0);
}

__device__ __forceinline__ bf16x4 cvt4(f32x4 v) {
    bf16x4 o;
    o[0] = (bf16)v[0]; o[1] = (bf16)v[1]; o[2] = (bf16)v[2]; o[3] = (bf16)v[3];
    return o;
}

// ---------------------------------------------------------------------------
// C = A * Bt^T + bias.  A:[M,K] fp32 row-major, Bt:[N,K] fp32 row-major
// (weight as stored), bias:[N] fp32.  Compute in bf16 MFMA, fp32 accumulate.
// mode 0: write out[m*N+n] (fp32)
// mode 1: qkv scatter to bf16 [BH,T,HD] buffers; q scaled by 1/8.
// Tiles: 64x64 per block (256 threads = 4 waves 2x2), K-step 64.
// ---------------------------------------------------------------------------
__global__ __launch_bounds__(256)
void gemm_bt(const float* __restrict__ A, const float* __restrict__ Bt,
             const float* __restrict__ bias, int K, int N, int mode,
             float* __restrict__ out, bf16* __restrict__ qb,
             bf16* __restrict__ kb, bf16* __restrict__ vb) {
    __shared__ __align__(16) bf16 As[64 * 72];
    __shared__ __align__(16) bf16 Bs[64 * 72];
    const int tid  = threadIdx.x;
    const int lane = tid & 63;
    const int wave = tid >> 6;
    const int quad = lane >> 4;
    const int l15  = lane & 15;
    const int wm = wave & 1, wn = wave >> 1;
    const int m0 = blockIdx.x * 64, n0 = blockIdx.y * 64;

    f32x4 acc[2][2] = {};

    const int sr = tid >> 2;          // 0..63 (row)
    const int sc = (tid & 3) * 16;    // 0,16,32,48 (col block of 16 floats)

    for (int k0 = 0; k0 < K; k0 += 64) {
#pragma unroll
        for (int j = 0; j < 4; j++) {
            f32x4 av = *(const f32x4*)&A[(long)(m0 + sr) * K + k0 + sc + j * 4];
            *(bf16x4*)&As[sr * 72 + sc + j * 4] = cvt4(av);
            f32x4 bv = *(const f32x4*)&Bt[(long)(n0 + sr) * K + k0 + sc + j * 4];
            *(bf16x4*)&Bs[sr * 72 + sc + j * 4] = cvt4(bv);
        }
        __syncthreads();
#pragma unroll
        for (int kk = 0; kk < 64; kk += 32) {
            bf16x8 a0 = *(const bf16x8*)&As[(wm * 32 + l15) * 72 + kk + quad * 8];
            bf16x8 a1 = *(const bf16x8*)&As[(wm * 32 + 16 + l15) * 72 + kk + quad * 8];
            bf16x8 b0 = *(const bf16x8*)&Bs[(wn * 32 + l15) * 72 + kk + quad * 8];
            bf16x8 b1 = *(const bf16x8*)&Bs[(wn * 32 + 16 + l15) * 72 + kk + quad * 8];
            acc[0][0] = mfma16(a0, b0, acc[0][0]);
            acc[0][1] = mfma16(a0, b1, acc[0][1]);
            acc[1][0] = mfma16(a1, b0, acc[1][0]);
            acc[1][1] = mfma16(a1, b1, acc[1][1]);
        }
        __syncthreads();
    }

    // Epilogue.  C/D layout: col = lane&15 (n), row = quad*4 + r (m).
#pragma unroll
    for (int mb = 0; mb < 2; mb++) {
#pragma unroll
        for (int nb = 0; nb < 2; nb++) {
            int n = n0 + wn * 32 + nb * 16 + l15;
            float bv = bias[n];
#pragma unroll
            for (int r = 0; r < 4; r++) {
                int m = m0 + wm * 32 + mb * 16 + quad * 4 + r;
                float v = acc[mb][nb][r] + bv;
                if (mode == 0) {
                    out[(long)m * N + n] = v;
                } else {
                    int t = m >> 2, b = m & 3;
                    int sec = n >> 9, j = n & 511;
                    int h = j >> 6, hd = j & 63;
                    long idx = ((long)(b * 8 + h) * T_DIM + t) * HD_DIM + hd;
                    if (sec == 0)      qb[idx] = (bf16)(v * 0.125f);  // 1/sqrt(64)
                    else if (sec == 1) kb[idx] = (bf16)v;
                    else               vb[idx] = (bf16)v;
                }
            }
        }
    }
}

// ---------------------------------------------------------------------------
// Flash-style attention with additive bias from dist[B,T,T,H] (fp32).
// Grid: 512 blocks, 1-D, XCD-swizzled: bid = h*64 + (b*16 + qt) so the 8
// head-siblings (same b,qt — they read the SAME dist cache lines) have ids
// differing by 64 == 0 (mod 8) and land on the same XCD under round-robin
// dispatch, sharing dist lines in that XCD's L2.
// Block = 256 threads = 4 waves, wave owns 16 Q-rows of a 64-row q-tile.
// Writes ctx[T][B][E] (fp32) with e = h*64+hd.
// ---------------------------------------------------------------------------
__global__ __launch_bounds__(256)
void attn_kernel(const bf16* __restrict__ qb, const bf16* __restrict__ kb,
                 const bf16* __restrict__ vb, const float* __restrict__ dist,
                 float* __restrict__ ctx) {
    __shared__ __align__(16) bf16 Ks[64 * 72];
    __shared__ __align__(16) bf16 Vts[64 * 72];
    __shared__ __align__(16) bf16 Ps[4 * 16 * 72];
    const int tid  = threadIdx.x;
    const int lane = tid & 63;
    const int wave = tid >> 6;
    const int quad = lane >> 4;
    const int l15  = lane & 15;
    const int bid = blockIdx.x;
    const int h   = bid >> 6;          // 0..7
    const int rem = bid & 63;
    const int b   = rem >> 4;          // 0..3
    const int qt  = rem & 15;          // 0..15
    const int bh  = b * 8 + h;
    const int qrow = qt * 64 + wave * 16 + l15;   // A-operand row (m = lane&15)

    // Q fragments: A[m=lane&15][k=quad*8+j]
    bf16x8 qa0 = *(const bf16x8*)&qb[((long)bh * T_DIM + qrow) * HD_DIM + quad * 8];
    bf16x8 qa1 = *(const bf16x8*)&qb[((long)bh * T_DIM + qrow) * HD_DIM + 32 + quad * 8];

    f32x4 oacc[4] = {};            // 4 hd-blocks of 16
    float mrun[4], lrun[4];        // per C-row (quad*4 + r)
#pragma unroll
    for (int r = 0; r < 4; r++) { mrun[r] = -INFINITY; lrun[r] = 0.f; }

    const int r0 = tid >> 3;          // 0..31
    const int c0 = (tid & 7) * 8;     // 0..56

    for (int st = 0; st < T_DIM; st += 64) {
        // Stage K tile [s_local][hd]
        *(bf16x8*)&Ks[r0 * 72 + c0] =
            *(const bf16x8*)&kb[((long)bh * T_DIM + st + r0) * HD_DIM + c0];
        *(bf16x8*)&Ks[(r0 + 32) * 72 + c0] =
            *(const bf16x8*)&kb[((long)bh * T_DIM + st + r0 + 32) * HD_DIM + c0];
        // Stage V tile transposed: Vts[hd][s_local]
        {
            bf16x8 v0 = *(const bf16x8*)&vb[((long)bh * T_DIM + st + r0) * HD_DIM + c0];
            bf16x8 v1 = *(const bf16x8*)&vb[((long)bh * T_DIM + st + r0 + 32) * HD_DIM + c0];
#pragma unroll
            for (int j = 0; j < 8; j++) {
                Vts[(c0 + j) * 72 + r0]      = v0[j];
                Vts[(c0 + j) * 72 + r0 + 32] = v1[j];
            }
        }
        __syncthreads();

        // S = Q*K^T  (M=16 q-rows, N=64 s, K=64 hd)
        f32x4 sacc[4] = {};
#pragma unroll
        for (int kk = 0; kk < 64; kk += 32) {
            bf16x8 a = (kk == 0) ? qa0 : qa1;
#pragma unroll
            for (int nb = 0; nb < 4; nb++) {
                bf16x8 bfr = *(const bf16x8*)&Ks[(nb * 16 + l15) * 72 + kk + quad * 8];
                sacc[nb] = mfma16(a, bfr, sacc[nb]);
            }
        }

        // Add bias (dist strided by H in last dim, fp32)
        float sv[4][4];
#pragma unroll
        for (int nb = 0; nb < 4; nb++) {
            int s = st + nb * 16 + l15;
#pragma unroll
            for (int r = 0; r < 4; r++) {
                int tq = qt * 64 + wave * 16 + quad * 4 + r;
                float d = dist[(((long)b * T_DIM + tq) * T_DIM + s) * H_DIM + h];
                sv[nb][r] = sacc[nb][r] + d;
            }
        }

        // Online softmax per row (row spread over the quad's 16 lanes)
#pragma unroll
        for (int r = 0; r < 4; r++) {
            float rm = fmaxf(fmaxf(sv[0][r], sv[1][r]), fmaxf(sv[2][r], sv[3][r]));
#pragma unroll
            for (int msk = 1; msk < 16; msk <<= 1)
                rm = fmaxf(rm, __shfl_xor(rm, msk));
            float mnew  = fmaxf(mrun[r], rm);
            float alpha = __expf(mrun[r] - mnew);
            mrun[r] = mnew;
            float rs = 0.f;
#pragma unroll
            for (int nb = 0; nb < 4; nb++) {
                float p = __expf(sv[nb][r] - mnew);
                sv[nb][r] = p;
                rs += p;
            }
#pragma unroll
            for (int msk = 1; msk < 16; msk <<= 1)
                rs += __shfl_xor(rs, msk);
            lrun[r] = lrun[r] * alpha + rs;
#pragma unroll
            for (int nb = 0; nb < 4; nb++)
                oacc[nb][r] *= alpha;
        }

        // P: C-layout -> LDS -> A-operand layout
        bf16* pw = &Ps[wave * 16 * 72];
#pragma unroll
        for (int nb = 0; nb < 4; nb++)
#pragma unroll
            for (int r = 0; r < 4; r++)
                pw[(quad * 4 + r) * 72 + nb * 16 + l15] = (bf16)sv[nb][r];
        __syncthreads();   // order P writes before A-fragment reads

        // O += P * V   (M=16 q-rows, N=64 hd, K=64 s)
#pragma unroll
        for (int kk = 0; kk < 64; kk += 32) {
            bf16x8 ap = *(const bf16x8*)&pw[l15 * 72 + kk + quad * 8];
#pragma unroll
            for (int nb = 0; nb < 4; nb++) {
                bf16x8 bv2 = *(const bf16x8*)&Vts[(nb * 16 + l15) * 72 + kk + quad * 8];
                oacc[nb] = mfma16(ap, bv2, oacc[nb]);
            }
        }
        __syncthreads();
    }

    // Epilogue: normalize and write ctx[t][b][h*64+hd] (fp32)
#pragma unroll
    for (int nb = 0; nb < 4; nb++) {
#pragma unroll
        for (int r = 0; r < 4; r++) {
            int t  = qt * 64 + wave * 16 + quad * 4 + r;
            int hd = nb * 16 + l15;
            float o = oacc[nb][r] / lrun[r];
            ctx[((long)t * B_DIM + b) * E_DIM + h * HD_DIM + hd] = o;
        }
    }
}

// ---------------------------------------------------------------------------
extern "C" void kernel_launch(void* const* d_in, const int* in_sizes, int n_in,
                              void* d_out, int out_size, void* d_ws, size_t ws_size,
                              hipStream_t stream) {
    const float* query = (const float*)d_in[0];   // [T,B,E]
    const float* dist  = (const float*)d_in[1];   // [B,T,T,H]
    const float* win   = (const float*)d_in[2];   // [3E,E]
    const float* bin   = (const float*)d_in[3];   // [3E]
    const float* wout  = (const float*)d_in[4];   // [E,E]
    const float* bout  = (const float*)d_in[5];   // [E]
    float* out = (float*)d_out;                   // [T,B,E]

    bf16* qb  = (bf16*)d_ws;                      // 3x bf16 [BH,T,HD] = 12 MB
    bf16* kb  = qb + (1 << 21);
    bf16* vb  = kb + (1 << 21);
    float* ctx = (float*)(vb + (1 << 21));        // fp32 [T,B,E] = 8 MB

    // QKV in-projection: M=4096, N=1536, K=512
    gemm_bt<<<dim3(64, 24), 256, 0, stream>>>(query, win, bin, 512, 1536, 1,
                                              nullptr, qb, kb, vb);
    // Attention: 512 blocks, XCD-swizzled so head-siblings share an XCD L2
    attn_kernel<<<dim3(512), 256, 0, stream>>>(qb, kb, vb, dist, ctx);
    // Out-projection: M=4096, N=512, K=512
    gemm_bt<<<dim3(64, 8), 256, 0, stream>>>(ctx, wout, bout, 512, 512, 0,
                                             out, nullptr, nullptr, nullptr);
}

// Round 4
// 304.811 us; speedup vs baseline: 1.1640x; 1.0345x over previous
//
#include <hip/hip_runtime.h>
#include <math.h>

typedef __bf16 bf16;
typedef bf16 bf16x8 __attribute__((ext_vector_type(8)));
typedef bf16 bf16x4 __attribute__((ext_vector_type(4)));
typedef float f32x4 __attribute__((ext_vector_type(4)));

// Problem constants
#define T_DIM 1024
#define B_DIM 4
#define E_DIM 512
#define H_DIM 8
#define HD_DIM 64
#define BH_DIM 32

__device__ __forceinline__ f32x4 mfma16(bf16x8 a, bf16x8 b, f32x4 c) {
    return __builtin_amdgcn_mfma_f32_16x16x32_bf16(a, b, c, 0, 0, 0);
}

__device__ __forceinline__ bf16x4 cvt4(f32x4 v) {
    bf16x4 o;
    o[0] = (bf16)v[0]; o[1] = (bf16)v[1]; o[2] = (bf16)v[2]; o[3] = (bf16)v[3];
    return o;
}

// ---------------------------------------------------------------------------
// C = A * Bt^T + bias.  A:[M,K] fp32 row-major, Bt:[N,K] fp32 row-major,
// bias:[N] fp32.  bf16 MFMA, fp32 accumulate.  Block tile TM x TN, 256
// threads = 4 waves in 2x2, wave tile (TM/2)x(TN/2), frags 16x16.
// MODE 0: out[m*N+n] = v (fp32)
// MODE 1: qkv scatter; q scaled 1/8 -> qb[bh][t][hd], kb[bh][t][hd],
//         V TRANSPOSED -> vb[bh][hd][t]  (so attention can stage V
//         coalesced without an LDS transpose).
// ---------------------------------------------------------------------------
template<int TM, int TN, int MODE>
__global__ __launch_bounds__(256)
void gemm_t(const float* __restrict__ A, const float* __restrict__ Bt,
            const float* __restrict__ bias, int K, int N,
            float* __restrict__ out, bf16* __restrict__ qb,
            bf16* __restrict__ kb, bf16* __restrict__ vb) {
    constexpr int FM = TM / 32, FN = TN / 32;
    __shared__ __align__(16) bf16 As[TM * 72];
    __shared__ __align__(16) bf16 Bs[TN * 72];
    const int tid  = threadIdx.x;
    const int lane = tid & 63;
    const int wave = tid >> 6;
    const int quad = lane >> 4;
    const int l15  = lane & 15;
    const int wm = wave & 1, wn = wave >> 1;
    const int m0 = blockIdx.x * TM, n0 = blockIdx.y * TN;

    f32x4 acc[FM][FN] = {};

    const int sr = tid >> 2;          // 0..63
    const int sc = (tid & 3) * 16;    // 0,16,32,48

    for (int k0 = 0; k0 < K; k0 += 64) {
#pragma unroll
        for (int p = 0; p < TM / 64; p++) {
            const float* src = &A[(long)(m0 + p * 64 + sr) * K + k0 + sc];
#pragma unroll
            for (int j = 0; j < 4; j++)
                *(bf16x4*)&As[(p * 64 + sr) * 72 + sc + j * 4] =
                    cvt4(*(const f32x4*)(src + j * 4));
        }
#pragma unroll
        for (int p = 0; p < TN / 64; p++) {
            const float* src = &Bt[(long)(n0 + p * 64 + sr) * K + k0 + sc];
#pragma unroll
            for (int j = 0; j < 4; j++)
                *(bf16x4*)&Bs[(p * 64 + sr) * 72 + sc + j * 4] =
                    cvt4(*(const f32x4*)(src + j * 4));
        }
        __syncthreads();
#pragma unroll
        for (int kk = 0; kk < 64; kk += 32) {
            bf16x8 af[FM], bf[FN];
#pragma unroll
            for (int mb = 0; mb < FM; mb++)
                af[mb] = *(const bf16x8*)&As[(wm * (TM / 2) + mb * 16 + l15) * 72 + kk + quad * 8];
#pragma unroll
            for (int nb = 0; nb < FN; nb++)
                bf[nb] = *(const bf16x8*)&Bs[(wn * (TN / 2) + nb * 16 + l15) * 72 + kk + quad * 8];
#pragma unroll
            for (int mb = 0; mb < FM; mb++)
#pragma unroll
                for (int nb = 0; nb < FN; nb++)
                    acc[mb][nb] = mfma16(af[mb], bf[nb], acc[mb][nb]);
        }
        __syncthreads();
    }

    // Epilogue.  C/D layout: col = lane&15 (n), row = quad*4 + r (m).
#pragma unroll
    for (int mb = 0; mb < FM; mb++) {
#pragma unroll
        for (int nb = 0; nb < FN; nb++) {
            int n = n0 + wn * (TN / 2) + nb * 16 + l15;
            float bv = bias[n];
#pragma unroll
            for (int r = 0; r < 4; r++) {
                int m = m0 + wm * (TM / 2) + mb * 16 + quad * 4 + r;
                float v = acc[mb][nb][r] + bv;
                if (MODE == 0) {
                    out[(long)m * N + n] = v;
                } else {
                    int t = m >> 2, b = m & 3;
                    int sec = n >> 9, j = n & 511;
                    int h = j >> 6, hd = j & 63;
                    int bh = b * 8 + h;
                    if (sec == 0)
                        qb[((long)bh * T_DIM + t) * HD_DIM + hd] = (bf16)(v * 0.125f);
                    else if (sec == 1)
                        kb[((long)bh * T_DIM + t) * HD_DIM + hd] = (bf16)v;
                    else
                        vb[((long)bh * HD_DIM + hd) * T_DIM + t] = (bf16)v;  // transposed
                }
            }
        }
    }
}

// ---------------------------------------------------------------------------
// Flash-style attention, software-pipelined: K/V/bias for tile i+1 are
// prefetched into registers while tile i computes.  V is pre-transposed in
// the qkv epilogue, so both K and Vt staging are coalesced b128.
// Grid 512 1-D, XCD-swizzled (bid = h*64 + b*16 + qt) so head-siblings
// share dist lines in one XCD L2.
// ---------------------------------------------------------------------------
__global__ __launch_bounds__(256)
void attn_kernel(const bf16* __restrict__ qb, const bf16* __restrict__ kb,
                 const bf16* __restrict__ vb, const float* __restrict__ dist,
                 float* __restrict__ ctx) {
    __shared__ __align__(16) bf16 Ks[64 * 72];
    __shared__ __align__(16) bf16 Vts[64 * 72];
    __shared__ __align__(16) bf16 Ps[4 * 16 * 72];
    const int tid  = threadIdx.x;
    const int lane = tid & 63;
    const int wave = tid >> 6;
    const int quad = lane >> 4;
    const int l15  = lane & 15;
    const int bid = blockIdx.x;
    const int h   = bid >> 6;
    const int rem = bid & 63;
    const int b   = rem >> 4;
    const int qt  = rem & 15;
    const int bh  = b * 8 + h;
    const int qrow = qt * 64 + wave * 16 + l15;

    bf16x8 qa0 = *(const bf16x8*)&qb[((long)bh * T_DIM + qrow) * HD_DIM + quad * 8];
    bf16x8 qa1 = *(const bf16x8*)&qb[((long)bh * T_DIM + qrow) * HD_DIM + 32 + quad * 8];

    f32x4 oacc[4] = {};
    float mrun[4], lrun[4];
#pragma unroll
    for (int r = 0; r < 4; r++) { mrun[r] = -INFINITY; lrun[r] = 0.f; }

    const int r0 = tid >> 3;          // 0..31
    const int c0 = (tid & 7) * 8;     // 0..56

    // Prefetch registers (tile 0)
    bf16x8 pk0, pk1, pv0, pv1;
    float pb[4][4];
    {
        const int st = 0;
        pk0 = *(const bf16x8*)&kb[((long)bh * T_DIM + st + r0) * HD_DIM + c0];
        pk1 = *(const bf16x8*)&kb[((long)bh * T_DIM + st + r0 + 32) * HD_DIM + c0];
        pv0 = *(const bf16x8*)&vb[((long)bh * HD_DIM + r0) * T_DIM + st + c0];
        pv1 = *(const bf16x8*)&vb[((long)bh * HD_DIM + r0 + 32) * T_DIM + st + c0];
        const int tqb = qt * 64 + wave * 16 + quad * 4;
#pragma unroll
        for (int nb = 0; nb < 4; nb++) {
            int s = st + nb * 16 + l15;
#pragma unroll
            for (int r = 0; r < 4; r++)
                pb[nb][r] = dist[(((long)b * T_DIM + tqb + r) * T_DIM + s) * H_DIM + h];
        }
    }

    for (int st = 0; st < T_DIM; st += 64) {
        __syncthreads();               // previous iteration's LDS reads done
        *(bf16x8*)&Ks[r0 * 72 + c0]        = pk0;
        *(bf16x8*)&Ks[(r0 + 32) * 72 + c0] = pk1;
        *(bf16x8*)&Vts[r0 * 72 + c0]        = pv0;
        *(bf16x8*)&Vts[(r0 + 32) * 72 + c0] = pv1;
        float cb[4][4];
#pragma unroll
        for (int nb = 0; nb < 4; nb++)
#pragma unroll
            for (int r = 0; r < 4; r++) cb[nb][r] = pb[nb][r];
        __syncthreads();               // staging visible

        // Prefetch next tile (latency hidden behind this tile's compute)
        if (st + 64 < T_DIM) {
            const int sn = st + 64;
            const int tqb = qt * 64 + wave * 16 + quad * 4;
#pragma unroll
            for (int nb = 0; nb < 4; nb++) {
                int s = sn + nb * 16 + l15;
#pragma unroll
                for (int r = 0; r < 4; r++)
                    pb[nb][r] = dist[(((long)b * T_DIM + tqb + r) * T_DIM + s) * H_DIM + h];
            }
            pk0 = *(const bf16x8*)&kb[((long)bh * T_DIM + sn + r0) * HD_DIM + c0];
            pk1 = *(const bf16x8*)&kb[((long)bh * T_DIM + sn + r0 + 32) * HD_DIM + c0];
            pv0 = *(const bf16x8*)&vb[((long)bh * HD_DIM + r0) * T_DIM + sn + c0];
            pv1 = *(const bf16x8*)&vb[((long)bh * HD_DIM + r0 + 32) * T_DIM + sn + c0];
        }

        // S = Q*K^T  (M=16 q-rows, N=64 s, K=64 hd)
        f32x4 sacc[4] = {};
#pragma unroll
        for (int kk = 0; kk < 64; kk += 32) {
            bf16x8 a = (kk == 0) ? qa0 : qa1;
#pragma unroll
            for (int nb = 0; nb < 4; nb++) {
                bf16x8 bfr = *(const bf16x8*)&Ks[(nb * 16 + l15) * 72 + kk + quad * 8];
                sacc[nb] = mfma16(a, bfr, sacc[nb]);
            }
        }

        float sv[4][4];
#pragma unroll
        for (int nb = 0; nb < 4; nb++)
#pragma unroll
            for (int r = 0; r < 4; r++)
                sv[nb][r] = sacc[nb][r] + cb[nb][r];

        // Online softmax per row (row spread over the quad's 16 lanes)
#pragma unroll
        for (int r = 0; r < 4; r++) {
            float rm = fmaxf(fmaxf(sv[0][r], sv[1][r]), fmaxf(sv[2][r], sv[3][r]));
#pragma unroll
            for (int msk = 1; msk < 16; msk <<= 1)
                rm = fmaxf(rm, __shfl_xor(rm, msk));
            float mnew  = fmaxf(mrun[r], rm);
            float alpha = __expf(mrun[r] - mnew);
            mrun[r] = mnew;
            float rs = 0.f;
#pragma unroll
            for (int nb = 0; nb < 4; nb++) {
                float p = __expf(sv[nb][r] - mnew);
                sv[nb][r] = p;
                rs += p;
            }
#pragma unroll
            for (int msk = 1; msk < 16; msk <<= 1)
                rs += __shfl_xor(rs, msk);
            lrun[r] = lrun[r] * alpha + rs;
#pragma unroll
            for (int nb = 0; nb < 4; nb++)
                oacc[nb][r] *= alpha;
        }

        // P: C-layout -> LDS -> A-operand layout (wave-private region; DS ops
        // from one wave complete in order, no barrier needed)
        bf16* pw = &Ps[wave * 16 * 72];
#pragma unroll
        for (int nb = 0; nb < 4; nb++)
#pragma unroll
            for (int r = 0; r < 4; r++)
                pw[(quad * 4 + r) * 72 + nb * 16 + l15] = (bf16)sv[nb][r];

        // O += P * V   (M=16 q-rows, N=64 hd, K=64 s)
#pragma unroll
        for (int kk = 0; kk < 64; kk += 32) {
            bf16x8 ap = *(const bf16x8*)&pw[l15 * 72 + kk + quad * 8];
#pragma unroll
            for (int nb = 0; nb < 4; nb++) {
                bf16x8 bv2 = *(const bf16x8*)&Vts[(nb * 16 + l15) * 72 + kk + quad * 8];
                oacc[nb] = mfma16(ap, bv2, oacc[nb]);
            }
        }
    }

    // Epilogue: normalize and write ctx[t][b][h*64+hd] (fp32)
#pragma unroll
    for (int nb = 0; nb < 4; nb++) {
#pragma unroll
        for (int r = 0; r < 4; r++) {
            int t  = qt * 64 + wave * 16 + quad * 4 + r;
            int hd = nb * 16 + l15;
            float o = oacc[nb][r] / lrun[r];
            ctx[((long)t * B_DIM + b) * E_DIM + h * HD_DIM + hd] = o;
        }
    }
}

// ---------------------------------------------------------------------------
extern "C" void kernel_launch(void* const* d_in, const int* in_sizes, int n_in,
                              void* d_out, int out_size, void* d_ws, size_t ws_size,
                              hipStream_t stream) {
    const float* query = (const float*)d_in[0];   // [T,B,E]
    const float* dist  = (const float*)d_in[1];   // [B,T,T,H]
    const float* win   = (const float*)d_in[2];   // [3E,E]
    const float* bin   = (const float*)d_in[3];   // [3E]
    const float* wout  = (const float*)d_in[4];   // [E,E]
    const float* bout  = (const float*)d_in[5];   // [E]
    float* out = (float*)d_out;                   // [T,B,E]

    bf16* qb  = (bf16*)d_ws;                      // [BH,T,HD] bf16
    bf16* kb  = qb + (1 << 21);                   // [BH,T,HD] bf16
    bf16* vb  = kb + (1 << 21);                   // [BH,HD,T] bf16 (transposed)
    float* ctx = (float*)(vb + (1 << 21));        // [T,B,E] fp32

    // QKV in-projection: M=4096, N=1536, K=512, 128x128 tiles
    gemm_t<128, 128, 1><<<dim3(32, 12), 256, 0, stream>>>(
        query, win, bin, 512, 1536, nullptr, qb, kb, vb);
    // Attention: 512 blocks, XCD-swizzled
    attn_kernel<<<dim3(512), 256, 0, stream>>>(qb, kb, vb, dist, ctx);
    // Out-projection: M=4096, N=512, K=512, 128x64 tiles
    gemm_t<128, 64, 0><<<dim3(32, 8), 256, 0, stream>>>(
        ctx, wout, bout, 512, 512, out, nullptr, nullptr, nullptr);
}